// Round 13
// baseline (47.507 us; speedup 1.0000x reference)
//
#include <hip/hip_runtime.h>
#include <math.h>

#define NBINS 513
#define NROWS 4000
#define BATCH 8
#define FPW   8                          // output rows per chain (1 wave = 1 chain)
#define CHAINS_PER_BATCH (NROWS / FPW)   // 500

typedef const __attribute__((address_space(1))) void* gvp;
typedef __attribute__((address_space(3))) void* lvp;

__device__ __forceinline__ void cmul(float& ar, float& ai, float br, float bi) {
    const float t = ar * br - ai * bi;
    ai = ar * bi + ai * br;
    ar = t;
}

// In-place inverse DFT-8 (omega = e^{+2pi i/8}) on 8 complex register values.
__device__ __forceinline__ void idft8(float* xr, float* xi) {
    const float S = 0.70710678118654752440f;
    float er[4], ei[4], orr[4], oi[4];
    #pragma unroll
    for (int j = 0; j < 4; ++j) {
        er[j]  = xr[j] + xr[j+4];  ei[j] = xi[j] + xi[j+4];
        orr[j] = xr[j] - xr[j+4];  oi[j] = xi[j] - xi[j+4];
    }
    const float f1r = S * (orr[1] - oi[1]), f1i = S * (orr[1] + oi[1]);
    const float f2r = -oi[2],               f2i = orr[2];
    const float f3r = S * (-orr[3] - oi[3]), f3i = S * (orr[3] - oi[3]);
    {   // DFT4 (w4 = +i) over evens -> y0,y2,y4,y6
        const float eer = er[0]+er[2], eei = ei[0]+ei[2];
        const float eor = er[0]-er[2], eoi = ei[0]-ei[2];
        const float oer = er[1]+er[3], oei = ei[1]+ei[3];
        const float oor = er[1]-er[3], ooi = ei[1]-ei[3];
        xr[0] = eer + oer;  xi[0] = eei + oei;
        xr[2] = eor - ooi;  xi[2] = eoi + oor;
        xr[4] = eer - oer;  xi[4] = eei - oei;
        xr[6] = eor + ooi;  xi[6] = eoi - oor;
    }
    {   // DFT4 over odds*w8 -> y1,y3,y5,y7
        const float eer = orr[0]+f2r, eei = oi[0]+f2i;
        const float eor = orr[0]-f2r, eoi = oi[0]-f2i;
        const float oer = f1r+f3r,    oei = f1i+f3i;
        const float oor = f1r-f3r,    ooi = f1i-f3i;
        xr[1] = eer + oer;  xi[1] = eei + oei;
        xr[3] = eor - ooi;  xi[3] = eoi + oor;
        xr[5] = eer - oer;  xi[5] = eei - oei;
        xr[7] = eor + ooi;  xi[7] = eoi - oor;
    }
}

// Butterfly via generic shuffle: P (reg-bit=0) on SEL lanes swaps with Q on !SEL.
#define BFLY_DPP(P, Q, SEL, CTRL) do {                                          \
    float t_ = (SEL) ? (P) : (Q);                                               \
    t_ = __int_as_float(__builtin_amdgcn_mov_dpp(__float_as_int(t_), (CTRL),    \
                                                 0xf, 0xf, true));              \
    (P) = (SEL) ? t_ : (P);                                                     \
    (Q) = (SEL) ? (Q) : t_;                                                     \
} while (0)

#define BFLY_SWZ(P, Q, SEL, PAT) do {                                           \
    float t_ = (SEL) ? (P) : (Q);                                               \
    t_ = __int_as_float(__builtin_amdgcn_ds_swizzle(__float_as_int(t_), (PAT)));\
    (P) = (SEL) ? t_ : (P);                                                     \
    (Q) = (SEL) ? (Q) : t_;                                                     \
} while (0)

// Distance-16/32 butterflies: prefer gfx950 permlane swap BUILTINS (compiler-
// managed hazards — the R12 hand-asm lacked wait states). Fallback: shfl_xor.
#if __has_builtin(__builtin_amdgcn_permlane16_swap)
#define BFLY_PL16(P, Q, SEL) do {                                               \
    auto r_ = __builtin_amdgcn_permlane16_swap(                                 \
        (unsigned)__float_as_uint(P), (unsigned)__float_as_uint(Q),             \
        false, false);                                                          \
    (P) = __uint_as_float(r_[0]); (Q) = __uint_as_float(r_[1]);                 \
} while (0)
#else
#define BFLY_PL16(P, Q, SEL) do {                                               \
    float t_ = (SEL) ? (P) : (Q);                                               \
    t_ = __shfl_xor(t_, 16, 64);                                                \
    (P) = (SEL) ? t_ : (P);                                                     \
    (Q) = (SEL) ? (Q) : t_;                                                     \
} while (0)
#endif

#if __has_builtin(__builtin_amdgcn_permlane32_swap)
#define BFLY_PL32(P, Q, SEL) do {                                               \
    auto r_ = __builtin_amdgcn_permlane32_swap(                                 \
        (unsigned)__float_as_uint(P), (unsigned)__float_as_uint(Q),             \
        false, false);                                                          \
    (P) = __uint_as_float(r_[0]); (Q) = __uint_as_float(r_[1]);                 \
} while (0)
#else
#define BFLY_PL32(P, Q, SEL) do {                                               \
    float t_ = (SEL) ? (P) : (Q);                                               \
    t_ = __shfl_xor(t_, 32, 64);                                                \
    (P) = (SEL) ? t_ : (P);                                                     \
    (Q) = (SEL) ? (Q) : t_;                                                     \
} while (0)
#endif

__global__ __launch_bounds__(64) void istft_kernel(
    const float* __restrict__ re, const float* __restrict__ im,
    float* __restrict__ out)
{
    __shared__ float st[2][2][516];    // [buf][re/im][bin 0..512] staging only

    const int u  = threadIdx.x;        // 0..63
    const int b  = blockIdx.y;
    const int t0 = blockIdx.x * FPW;

    const int k1 = u >> 3;
    const int su = ((u & 7) << 3) | k1;   // bit-swapped lane index

    // ---- per-thread twiddles (registers) ----
    const float w0 = 6.283185307179586476925f / 1024.0f;
    const float F  = 4.8828125e-4f;    // 0.5 (harness) * packed-irfft norm

    float2 twn[8];                     // F * i * w1024^(u+64j)  (pack rotation)
    #pragma unroll
    for (int j = 0; j < 8; ++j) {
        float s, c; sincosf(w0 * (float)(u + 64 * j), &s, &c);
        twn[j] = make_float2(-F * s, F * c);
    }
    float2 wA, wB;                     // stage-2 / stage-3 twiddle recurrence bases
    {
        float s, c;
        sincosf(w0 * (float)(16 * k1), &s, &c); wA = make_float2(c, s);  // e^{2pi i k1/64}
        sincosf(w0 * (float)(2 * su), &s, &c);  wB = make_float2(c, s);  // e^{2pi i su/512}
    }

    float2 cc[4];                      // OLA carry (registers)
    #pragma unroll
    for (int m = 0; m < 4; ++m) cc[m] = make_float2(0.f, 0.f);

    const float* rebase = re + (size_t)b * NROWS * NBINS;
    const float* imbase = im + (size_t)b * NROWS * NBINS;

    // ---- async staging of one spectrum row into LDS (size=4: alignment-safe) ----
    auto stage = [&](int t, int buf) {
        const float* rp = rebase + (size_t)t * NBINS;
        const float* ip = imbase + (size_t)t * NBINS;
        #pragma unroll
        for (int jj = 0; jj < 8; ++jj)
            __builtin_amdgcn_global_load_lds((gvp)(rp + 64 * jj + u),
                                             (lvp)&st[buf][0][64 * jj], 4, 0, 0);
        __builtin_amdgcn_global_load_lds((gvp)(rp + 449 + u),
                                         (lvp)&st[buf][0][449], 4, 0, 0);
        #pragma unroll
        for (int jj = 0; jj < 8; ++jj)
            __builtin_amdgcn_global_load_lds((gvp)(ip + 64 * jj + u),
                                             (lvp)&st[buf][1][64 * jj], 4, 0, 0);
        __builtin_amdgcn_global_load_lds((gvp)(ip + 449 + u),
                                         (lvp)&st[buf][1][449], 4, 0, 0);
    };  // 18 vmcnt entries per frame

    // ---- prologue: stage the priming frame ----
    if (t0 == 0) {
        #pragma unroll
        for (int j = 0; j < 8; ++j) { st[0][0][u + 64 * j] = 0.f; st[0][1][u + 64 * j] = 0.f; }
        if (u == 0) { st[0][0][512] = 0.f; st[0][1][512] = 0.f; }
    } else {
        stage(t0 - 1, 0);
    }
    asm volatile("s_waitcnt vmcnt(0)" ::: "memory");

    const bool s1  = (u & 1)  != 0;
    const bool s2  = (u & 2)  != 0;
    const bool s4  = (u & 4)  != 0;
    const bool s8  = (u & 8)  != 0;
    const bool s16 = (u & 16) != 0; (void)s16;
    const bool s32 = (u & 32) != 0; (void)s32;

    for (int it = 0; it <= FPW; ++it) {
        const int t = t0 - 1 + it;
        const int c = it & 1;

        // ---- wait for frame t's staging: 18 loads must be done.
        // steady-state queue = [stage(t):18][stores(t-1):4] -> vmcnt(4).
        if (it >= 2)      { asm volatile("s_waitcnt vmcnt(4)" ::: "memory"); }
        else if (it == 1) { asm volatile("s_waitcnt vmcnt(0)" ::: "memory"); }

        // ---- pack from staged LDS row: z = F*e + twn*h  (k = u + 64j) ----
        float zr8[8], zi8[8];
        {
            const float* fr = st[c][0];
            const float* fi = st[c][1];
            #pragma unroll
            for (int j = 0; j < 8; ++j) {
                const int k = u + 64 * j;
                float xr = fr[k], xi = fi[k];
                float rc = fr[512 - k], ic = -fi[512 - k];
                if (k == 0) { xi = 0.f; ic = 0.f; }   // pocketfft c2r: Im ignored
                const float er0 = xr + rc, ei0 = xi + ic;
                const float hr0 = xr - rc, hi0 = xi - ic;
                zr8[j] = F * er0 + (twn[j].x * hr0 - twn[j].y * hi0);
                zi8[j] = F * ei0 + (twn[j].x * hi0 + twn[j].y * hr0);
            }
        }

        // ---- issue next frame's staging; latency hides under the FFT ----
        if (it < FPW) stage(t + 1, c ^ 1);

        // ---- stage 1: IDFT8 over regs (weight-64 digit) — no twiddle ----
        idft8(zr8, zi8);

        // ---- T1: transpose (reg-digit <-> lane bits 3-5), pure cross-lane ----
        // round bit0: lane distance 8 (DPP row_ror:8 == xor-8 within 16-lane rows)
        BFLY_DPP(zr8[0], zr8[1], s8, 0x128); BFLY_DPP(zi8[0], zi8[1], s8, 0x128);
        BFLY_DPP(zr8[2], zr8[3], s8, 0x128); BFLY_DPP(zi8[2], zi8[3], s8, 0x128);
        BFLY_DPP(zr8[4], zr8[5], s8, 0x128); BFLY_DPP(zi8[4], zi8[5], s8, 0x128);
        BFLY_DPP(zr8[6], zr8[7], s8, 0x128); BFLY_DPP(zi8[6], zi8[7], s8, 0x128);
        // round bit1: lane distance 16
        BFLY_PL16(zr8[0], zr8[2], s16); BFLY_PL16(zi8[0], zi8[2], s16);
        BFLY_PL16(zr8[1], zr8[3], s16); BFLY_PL16(zi8[1], zi8[3], s16);
        BFLY_PL16(zr8[4], zr8[6], s16); BFLY_PL16(zi8[4], zi8[6], s16);
        BFLY_PL16(zr8[5], zr8[7], s16); BFLY_PL16(zi8[5], zi8[7], s16);
        // round bit2: lane distance 32
        BFLY_PL32(zr8[0], zr8[4], s32); BFLY_PL32(zi8[0], zi8[4], s32);
        BFLY_PL32(zr8[1], zr8[5], s32); BFLY_PL32(zi8[1], zi8[5], s32);
        BFLY_PL32(zr8[2], zr8[6], s32); BFLY_PL32(zi8[2], zi8[6], s32);
        BFLY_PL32(zr8[3], zr8[7], s32); BFLY_PL32(zi8[3], zi8[7], s32);

        // ---- stage 2: twiddle wA^r then IDFT8 over regs (weight-8 digit) ----
        {
            float tr = wA.x, ti = wA.y;
            #pragma unroll
            for (int r = 1; r < 8; ++r) {
                cmul(zr8[r], zi8[r], tr, ti);
                cmul(tr, ti, wA.x, wA.y);
            }
        }
        idft8(zr8, zi8);

        // ---- T2: transpose (reg-digit <-> lane bits 0-2) ----
        // round bit0: lane distance 1 (quad_perm [1,0,3,2])
        BFLY_DPP(zr8[0], zr8[1], s1, 0xB1); BFLY_DPP(zi8[0], zi8[1], s1, 0xB1);
        BFLY_DPP(zr8[2], zr8[3], s1, 0xB1); BFLY_DPP(zi8[2], zi8[3], s1, 0xB1);
        BFLY_DPP(zr8[4], zr8[5], s1, 0xB1); BFLY_DPP(zi8[4], zi8[5], s1, 0xB1);
        BFLY_DPP(zr8[6], zr8[7], s1, 0xB1); BFLY_DPP(zi8[6], zi8[7], s1, 0xB1);
        // round bit1: lane distance 2 (quad_perm [2,3,0,1])
        BFLY_DPP(zr8[0], zr8[2], s2, 0x4E); BFLY_DPP(zi8[0], zi8[2], s2, 0x4E);
        BFLY_DPP(zr8[1], zr8[3], s2, 0x4E); BFLY_DPP(zi8[1], zi8[3], s2, 0x4E);
        BFLY_DPP(zr8[4], zr8[6], s2, 0x4E); BFLY_DPP(zi8[4], zi8[6], s2, 0x4E);
        BFLY_DPP(zr8[5], zr8[7], s2, 0x4E); BFLY_DPP(zi8[5], zi8[7], s2, 0x4E);
        // round bit2: lane distance 4 (ds_swizzle xor-4, guide-verified pattern)
        BFLY_SWZ(zr8[0], zr8[4], s4, 0x101F); BFLY_SWZ(zi8[0], zi8[4], s4, 0x101F);
        BFLY_SWZ(zr8[1], zr8[5], s4, 0x101F); BFLY_SWZ(zi8[1], zi8[5], s4, 0x101F);
        BFLY_SWZ(zr8[2], zr8[6], s4, 0x101F); BFLY_SWZ(zi8[2], zi8[6], s4, 0x101F);
        BFLY_SWZ(zr8[3], zr8[7], s4, 0x101F); BFLY_SWZ(zi8[3], zi8[7], s4, 0x101F);

        // ---- stage 3: twiddle wB^r then IDFT8 over regs (weight-1 digit) ----
        {
            float tr = wB.x, ti = wB.y;
            #pragma unroll
            for (int r = 1; r < 8; ++r) {
                cmul(zr8[r], zi8[r], tr, ti);
                cmul(tr, ti, wB.x, wB.y);
            }
        }
        idft8(zr8, zi8);
        // reg r now holds z[su + 64*r]

        // ---- overlap-add, carry in registers; float2 slot = su + 64*m ----
        if (it >= 1) {
            float2* orow = (float2*)(out + ((size_t)b * NROWS + (size_t)t) * 512);
            #pragma unroll
            for (int m = 0; m < 4; ++m)
                orow[su + 64 * m] = make_float2(zr8[m] + cc[m].x, zi8[m] + cc[m].y);
        }
        #pragma unroll
        for (int m = 0; m < 4; ++m) cc[m] = make_float2(zr8[m + 4], zi8[m + 4]);
    }
}

extern "C" void kernel_launch(void* const* d_in, const int* in_sizes, int n_in,
                              void* d_out, int out_size, void* d_ws, size_t ws_size,
                              hipStream_t stream) {
    const float* re = (const float*)d_in[0];
    const float* im = (const float*)d_in[1];
    float* out = (float*)d_out;
    dim3 grid(CHAINS_PER_BATCH, BATCH);
    istft_kernel<<<grid, 64, 0, stream>>>(re, im, out);
}